// Round 2
// baseline (363.049 us; speedup 1.0000x reference)
//
#include <hip/hip_runtime.h>

// SNN direction decoder — fused MFMA GEMM + LIF scan + FC2.
// B=256, T=100, I=512, H=1024, C=8.
// R7: R6 structure + (a) T2 XOR-swizzle on the k-fragment LDS layout
// (involution swz(a)=a^(((a>>7)&7)<<4) bytes; write side realized by
// permuting per-lane GLOBAL source lp=lane^((lane>>3)&7), LDS dest linear
// per rule 21; read side ra/rb ^= ((l31>>2)&7)<<3 halfs) — kills the
// 6.29M-cycle 8-way bank conflict of R6; (b) epilogue Cs staging cut to
// [32][256] (4 phases of 32 t-rows) so LDS union = 48 KB -> 3 blocks/CU.
// K-loop: 32x32x16 f16 MFMA, block tile 128(t) x 256(h), 4 waves with
// 64x128 wave tiles; per 16-half chunk stage {Ah,Al,Bh,Bl} once, fire all
// 3 emulation products (xh*wh + xh*wl + xl*wh). Double-buffered LDS with
// counted s_waitcnt vmcnt(6) + raw s_barrier; vmcnt(0) only at last chunk.
// fp32 GEMM emulated as 3-term f16 (inputs pre-scaled 2^6, un-scaled 2^-12).

#define B_   256
#define T_   100
#define I_   512
#define H_   1024
#define C_   8
#define M_   (B_ * T_)        // 25600
#define KS_  1024             // stored split width [hi|lo]
#define SC   64.0f            // 2^6 pre-scale
#define ISC  (1.0f / 4096.0f) // 2^-12 epilogue un-scale

typedef _Float16 half8 __attribute__((ext_vector_type(8)));
typedef float floatx16 __attribute__((ext_vector_type(16)));

__device__ __forceinline__ void ld_g2l(const _Float16* g, _Float16* l) {
    // async global->LDS, 16B/lane; LDS dest = wave-uniform base + lane*16
    __builtin_amdgcn_global_load_lds(
        (const __attribute__((address_space(1))) void*)g,
        (__attribute__((address_space(3))) void*)l, 16, 0, 0);
}

// Rows 0..25599: x -> Asp[row][hi|lo]; rows 25600..26623: W1 -> same buffer
// (Wsp region starts at Asp + 25600*1024). Blocks 0..7 also init logits.
__global__ void __launch_bounds__(256)
split_all(const float* __restrict__ x, const float* __restrict__ W1,
          const float* __restrict__ b2, _Float16* __restrict__ Asp,
          float* __restrict__ out) {
    int g = blockIdx.x * 256 + threadIdx.x;   // (M_+H_)*64 threads
    if (g < B_ * C_) out[g] = 100.0f * b2[g & (C_ - 1)];
    int row = g >> 6;
    int i0 = (g & 63) * 8;
    const float* src = (row < M_) ? (x + (size_t)row * I_ + i0)
                                  : (W1 + (size_t)(row - M_) * I_ + i0);
    float4 v0 = *(const float4*)(src);
    float4 v1 = *(const float4*)(src + 4);
    float vv[8] = {v0.x, v0.y, v0.z, v0.w, v1.x, v1.y, v1.z, v1.w};
    half8 hi, lo;
#pragma unroll
    for (int j = 0; j < 8; ++j) {
        float s = vv[j] * SC;
        _Float16 h = (_Float16)s;
        hi[j] = h;
        lo[j] = (_Float16)(s - (float)h);
    }
    _Float16* r = Asp + (size_t)row * KS_ + i0;
    *(half8*)(r) = hi;
    *(half8*)(r + 512) = lo;
}

#define MFMA32(A, Bv, Cacc) \
    Cacc = __builtin_amdgcn_mfma_f32_32x32x16_f16(A, Bv, Cacc, 0, 0, 0)

// One chunk = 16 k-halfs of each of {Ah, Al, Bh, Bl}.
// LDS buf layout (halfs): Ah[128*16] @0 | Al @2048 | Bh[256*16] @4096 | Bl @8192.
// All staging windows (512 halfs = 1024 B each) are 1024B-aligned, so the
// swizzle involution acts window-locally on both sides.
#define STAGE(dd, koff) do {                                         \
    _Float16* lb = &sm.buf[0][0] + (dd) * 12288;                     \
    ld_g2l(ga0 + (koff), lb + w * 512);                              \
    ld_g2l(ga1 + (koff), lb + 2048 + w * 512);                       \
    ld_g2l(gb00 + (koff), lb + 4096 + w * 1024);                     \
    ld_g2l(gb01 + (koff), lb + 4096 + w * 1024 + 512);               \
    ld_g2l(gb10 + (koff), lb + 8192 + w * 1024);                     \
    ld_g2l(gb11 + (koff), lb + 8192 + w * 1024 + 512);               \
} while (0)

#define COMPUTE(dd) do {                                             \
    const _Float16* bb = &sm.buf[0][0] + (dd) * 12288;               \
    half8 ah[2], al[2], bh[4], bl[4];                                \
    _Pragma("unroll")                                                \
    for (int f = 0; f < 2; ++f) {                                    \
        ah[f] = *(const half8*)(bb + ra + f * 512);                  \
        al[f] = *(const half8*)(bb + 2048 + ra + f * 512);           \
    }                                                                \
    _Pragma("unroll")                                                \
    for (int f = 0; f < 4; ++f) {                                    \
        bh[f] = *(const half8*)(bb + 4096 + rb + f * 512);           \
        bl[f] = *(const half8*)(bb + 8192 + rb + f * 512);           \
    }                                                                \
    _Pragma("unroll")                                                \
    for (int fm = 0; fm < 2; ++fm) {                                 \
        _Pragma("unroll")                                            \
        for (int fn = 0; fn < 4; ++fn) {                             \
            MFMA32(ah[fm], bh[fn], acc[fm][fn]);                     \
            MFMA32(ah[fm], bl[fn], acc[fm][fn]);                     \
            MFMA32(al[fm], bh[fn], acc[fm][fn]);                     \
        }                                                            \
    }                                                                \
} while (0)

// Fused: C-tile[t 0..127][256 h], then LIF scan + FC2. One batch per block,
// 4 h-tiles of 256. XCD-swizzled: xcd=blk&7 owns batches [32*xcd, 32*xcd+32).
// A rows 100..127 overread into next batch / Wsp (masked in scan).
__global__ void __launch_bounds__(256, 3)
snn_mfma(const _Float16* __restrict__ Asp, const _Float16* __restrict__ Wsp,
         const float* __restrict__ b1, const float* __restrict__ W2,
         float* __restrict__ logits) {
    __shared__ union {
        __align__(16) _Float16 buf[2][12288];  // double-buffered chunk (48 KB)
        float Cs[32 * 256];                    // epilogue staging (32 KB)
    } sm;
    const int tid = threadIdx.x;
    const int lane = tid & 63;
    const int w = tid >> 6;

    const int xcd = blockIdx.x & 7;
    const int jj = blockIdx.x >> 3;        // 0..127 per-XCD sequence
    const int b  = xcd * 32 + (jj >> 2);   // batch 0..255
    const int n0 = (jj & 3) * 256;         // h tile offset

    const int wm = (w >> 1) * 64;   // wave's 64x128 sub-tile
    const int wn = (w & 1) * 128;
    const int l31 = lane & 31;
    const int q2 = lane >> 5;

    // ---- staging pointers (write side of the swizzle) ----
    // lane permutation: lane l loads the data that belongs at the LDS slot
    // it linearly writes (lp ^ ((lp>>3)&7) == lane).
    const int lp = lane ^ ((lane >> 3) & 7);
    const int rl = lp >> 1;
    const int cl8 = (lp & 1) * 8;
    const _Float16* ga0 = Asp + (size_t)(b * T_ + w * 32 + rl) * KS_ + cl8;
    const _Float16* ga1 = ga0 + 512;
    const _Float16* gb00 = Wsp + (size_t)(n0 + w * 64 + rl) * KS_ + cl8;
    const _Float16* gb01 = gb00 + 32 * KS_;
    const _Float16* gb10 = gb00 + 512;
    const _Float16* gb11 = gb01 + 512;

    // ---- fragment LDS offsets (read side of the swizzle), half units ----
    // raw = row*16 + q2*8; swizzled: XOR 16B-quad bits (3..5) with row bits
    // 2..4 (= addr bits 6..8). All later offsets (f*512, region bases,
    // dd*12288) are multiples of 512 halfs -> commute with the XOR.
    const int swz = ((l31 >> 2) & 7) << 3;
    const int ra = (((wm + l31) * 16) + q2 * 8) ^ swz;
    const int rb = (((wn + l31) * 16) + q2 * 8) ^ swz;

    floatx16 acc[2][4];
#pragma unroll
    for (int i = 0; i < 2; ++i)
#pragma unroll
        for (int j = 0; j < 4; ++j)
#pragma unroll
            for (int e = 0; e < 16; ++e) acc[i][j][e] = 0.f;

    STAGE(0, 0);
#pragma unroll 2
    for (int c = 0; c < 31; ++c) {
        const int d = c & 1;
        STAGE(d ^ 1, (c + 1) * 16);
        asm volatile("s_waitcnt vmcnt(6)" ::: "memory");
        __builtin_amdgcn_s_barrier();
        COMPUTE(d);
        __builtin_amdgcn_s_barrier();
        asm volatile("" ::: "memory");
    }
    asm volatile("s_waitcnt vmcnt(0)" ::: "memory");
    __builtin_amdgcn_s_barrier();
    COMPUTE(1);
    __syncthreads();   // full fence: all ds reads/loads done before Cs overwrite

    // ---- epilogue: acc -> LDS (four 32-row phases) -> LIF scan + FC2 ----
    float b1c[4];
#pragma unroll
    for (int fn = 0; fn < 4; ++fn) b1c[fn] = b1[n0 + wn + fn * 32 + l31];

    float mem = 0.f, ss = 0.f;

    // phase p covers tile rows [32p, 32p+32): written by waves 0,1 (wm=0)
    // for p<2 with fm=p, by waves 2,3 for p>=2 with fm=p-2.
#pragma unroll
    for (int p = 0; p < 4; ++p) {
        const int fm = p & 1;
        if ((w >> 1) == (p >> 1)) {
#pragma unroll
            for (int r = 0; r < 16; ++r) {
                const int row = (r & 3) + 8 * (r >> 2) + 4 * q2;  // 0..31
                float* dst = &sm.Cs[row * 256 + wn + l31];
#pragma unroll
                for (int fn = 0; fn < 4; ++fn)
                    dst[fn * 32] = acc[fm][fn][r] * ISC + b1c[fn];
            }
        }
        __syncthreads();
        const int nt = (p == 3) ? 4 : 32;   // t 96..99 only in last phase
#pragma unroll 8
        for (int t = 0; t < nt; ++t) {
            float cv = sm.Cs[t * 256 + tid];
            float reset = (mem > 1.0f) ? 1.0f : 0.0f;
            mem = 0.9f * mem + cv - reset;
            ss += (mem > 1.0f) ? 1.0f : 0.0f;
        }
        __syncthreads();
    }

    // ---- FC2: logits[b][c] += sum_h ss * W2[c][h] ----
#pragma unroll
    for (int cc = 0; cc < C_; ++cc) {
        float v = ss * W2[cc * H_ + n0 + tid];
#pragma unroll
        for (int off = 32; off; off >>= 1) v += __shfl_down(v, off, 64);
        if (lane == 0) atomicAdd(&logits[b * C_ + cc], v);
    }
}

extern "C" void kernel_launch(void* const* d_in, const int* in_sizes, int n_in,
                              void* d_out, int out_size, void* d_ws, size_t ws_size,
                              hipStream_t stream) {
    const float* x  = (const float*)d_in[0];
    const float* W1 = (const float*)d_in[1];
    const float* b1 = (const float*)d_in[2];
    const float* W2 = (const float*)d_in[3];
    const float* b2 = (const float*)d_in[4];
    float* out = (float*)d_out;

    // workspace: Asp [25600][1024] f16, Wsp [1024][1024] f16 directly after
    // (fused kernel's tail rows overread into Wsp by design).
    char* ws = (char*)d_ws;
    _Float16* Asp = (_Float16*)ws;
    _Float16* Wsp = (_Float16*)(ws + (size_t)M_ * KS_ * 2);

    hipLaunchKernelGGL(split_all, dim3((M_ + H_) * 64 / 256), dim3(256), 0, stream,
                       x, W1, b2, Asp, out);
    hipLaunchKernelGGL(snn_mfma, dim3(B_ * 4), dim3(256), 0, stream,
                       Asp, Wsp, b1, W2, out);
}

// Round 4
// 240.394 us; speedup vs baseline: 1.5102x; 1.5102x over previous
//
#include <hip/hip_runtime.h>

// SNN direction decoder — fused MFMA GEMM + LIF scan + FC2.
// B=256, T=100, I=512, H=1024, C=8.
// R8 (resubmit; R8 bench was an infra failure, no signal): combine R5's
// occupancy with R6's dedup'd staging.
//  - Block tile 128(t) x 128(h), grid B_*8 (R5 shape), 4 waves of 64x64
//    tiles using 32x32x16 f16 MFMA -> acc = 64 regs/thread, total ~140
//    unified regs -> 3 waves/SIMD (R6's 64x128 tile needed 232 -> 2).
//  - Per 16-half k-chunk stage {Ah,Al,Bh,Bl} ONCE, fire all 3 emulation
//    products from the same fragments (xh*wh + xh*wl + xl*wh): LDS port
//    traffic ~40 us/CU vs R5's ~57.
//  - Double-buffered 16KB chunks, counted s_waitcnt vmcnt(4) + raw
//    s_barrier (loads for chunk c+1 in flight across COMPUTE(c)).
//  - Swizzle pair (bank-verified: 4 lanes per 16B quad, conflict-free
//    b128): read addr ^= ((l31>>2)&7)<<3 (halfs), write side via per-lane
//    GLOBAL source permutation lp=lane^((lane>>3)&7) with linear
//    gload_lds dest (rule 21).
//  - __launch_bounds__(256,2): cap 256 regs (R7's (256,3) caused a 601MB
//    scratch-spill catastrophe at 232 regs needed).
// fp32 GEMM emulated as 3-term f16 (inputs pre-scaled 2^6, un-scaled 2^-12).

#define B_   256
#define T_   100
#define I_   512
#define H_   1024
#define C_   8
#define M_   (B_ * T_)        // 25600
#define KS_  1024             // stored split width [hi|lo]
#define SC   64.0f            // 2^6 pre-scale
#define ISC  (1.0f / 4096.0f) // 2^-12 epilogue un-scale

typedef _Float16 half8 __attribute__((ext_vector_type(8)));
typedef float floatx16 __attribute__((ext_vector_type(16)));

__device__ __forceinline__ void ld_g2l(const _Float16* g, _Float16* l) {
    // async global->LDS, 16B/lane; LDS dest = wave-uniform base + lane*16
    __builtin_amdgcn_global_load_lds(
        (const __attribute__((address_space(1))) void*)g,
        (__attribute__((address_space(3))) void*)l, 16, 0, 0);
}

// Rows 0..25599: x -> Asp[row][hi|lo]; rows 25600..26623: W1 -> same buffer
// (Wsp region starts at Asp + 25600*1024). Blocks 0..7 also init logits.
__global__ void __launch_bounds__(256)
split_all(const float* __restrict__ x, const float* __restrict__ W1,
          const float* __restrict__ b2, _Float16* __restrict__ Asp,
          float* __restrict__ out) {
    int g = blockIdx.x * 256 + threadIdx.x;   // (M_+H_)*64 threads
    if (g < B_ * C_) out[g] = 100.0f * b2[g & (C_ - 1)];
    int row = g >> 6;
    int i0 = (g & 63) * 8;
    const float* src = (row < M_) ? (x + (size_t)row * I_ + i0)
                                  : (W1 + (size_t)(row - M_) * I_ + i0);
    float4 v0 = *(const float4*)(src);
    float4 v1 = *(const float4*)(src + 4);
    float vv[8] = {v0.x, v0.y, v0.z, v0.w, v1.x, v1.y, v1.z, v1.w};
    half8 hi, lo;
#pragma unroll
    for (int j = 0; j < 8; ++j) {
        float s = vv[j] * SC;
        _Float16 h = (_Float16)s;
        hi[j] = h;
        lo[j] = (_Float16)(s - (float)h);
    }
    _Float16* r = Asp + (size_t)row * KS_ + i0;
    *(half8*)(r) = hi;
    *(half8*)(r + 512) = lo;
}

#define MFMA32(A, Bv, Cacc) \
    Cacc = __builtin_amdgcn_mfma_f32_32x32x16_f16(A, Bv, Cacc, 0, 0, 0)

// One chunk = 16 k-halfs of each of {Ah, Al, Bh, Bl}.
// LDS buffer (halfs): Ah[128*16] @0 | Al @2048 | Bh[128*16] @4096 | Bl @6144.
// Buffer stride 8192 halfs (16 KB). Each wave stages one 32-row window
// (1024 B contiguous, aligned) per region -> 4 gload_lds/wave/chunk.
#define STAGE(dd, koff) do {                                         \
    _Float16* lb = &sm.buf[0][0] + (dd) * 8192 + w * 512;            \
    ld_g2l(gah + (koff), lb);                                        \
    ld_g2l(gal + (koff), lb + 2048);                                 \
    ld_g2l(gbh + (koff), lb + 4096);                                 \
    ld_g2l(gbl + (koff), lb + 6144);                                 \
} while (0)

// (ra + f*512 is safe: f*512 is a multiple of 512 halfs, above the XOR bits)
#define COMPUTE(dd) do {                                             \
    const _Float16* bb = &sm.buf[0][0] + (dd) * 8192;                \
    half8 ah[2], al[2], bh[2], bl[2];                                \
    _Pragma("unroll")                                                \
    for (int f = 0; f < 2; ++f) {                                    \
        ah[f] = *(const half8*)(bb + ra + f * 512);                  \
        al[f] = *(const half8*)(bb + 2048 + ra + f * 512);           \
        bh[f] = *(const half8*)(bb + 4096 + rb + f * 512);           \
        bl[f] = *(const half8*)(bb + 6144 + rb + f * 512);           \
    }                                                                \
    _Pragma("unroll")                                                \
    for (int fm = 0; fm < 2; ++fm) {                                 \
        _Pragma("unroll")                                            \
        for (int fn = 0; fn < 2; ++fn) {                             \
            MFMA32(ah[fm], bh[fn], acc[fm][fn]);                     \
            MFMA32(ah[fm], bl[fn], acc[fm][fn]);                     \
            MFMA32(al[fm], bh[fn], acc[fm][fn]);                     \
        }                                                            \
    }                                                                \
} while (0)

// Fused: C-tile[t 0..127][128 h], then LIF scan + FC2. One batch per block,
// 8 h-tiles of 128. XCD-swizzled: xcd=blk&7 owns batches [32*xcd, 32*xcd+32).
// A rows 100..127 overread into next batch / Wsp (masked in scan).
__global__ void __launch_bounds__(256, 2)
snn_mfma(const _Float16* __restrict__ Asp, const _Float16* __restrict__ Wsp,
         const float* __restrict__ b1, const float* __restrict__ W2,
         float* __restrict__ logits) {
    __shared__ union {
        __align__(16) _Float16 buf[2][8192];   // double-buffered chunk (32 KB)
        float Cs[32 * 128];                    // epilogue staging (16 KB)
    } sm;
    const int tid = threadIdx.x;
    const int lane = tid & 63;
    const int w = tid >> 6;

    const int xcd = blockIdx.x & 7;
    const int jj = blockIdx.x >> 3;        // 0..255 per-XCD sequence
    const int b  = xcd * 32 + (jj >> 3);   // batch 0..255
    const int n0 = (jj & 7) * 128;         // h tile offset

    const int wm = (w >> 1) * 64;   // wave's 64x64 sub-tile
    const int wn = (w & 1) * 64;
    const int l31 = lane & 31;
    const int q2 = lane >> 5;

    // ---- staging pointers (write side of the swizzle) ----
    // lane permutation: lane l's gload_lds writes LDS cell l; it must carry
    // the data for logical cell lp = l ^ ((l>>3)&7) (involution; the XOR key
    // bits 3..5 are unchanged by the XOR).
    const int lp = lane ^ ((lane >> 3) & 7);
    const int rl = lp >> 1;          // row within the 32-row window
    const int cl8 = (lp & 1) * 8;    // which 8-half group of the 16-half slice
    const _Float16* gah = Asp + (size_t)(b * T_ + w * 32 + rl) * KS_ + cl8;
    const _Float16* gal = gah + 512;
    const _Float16* gbh = Wsp + (size_t)(n0 + w * 32 + rl) * KS_ + cl8;
    const _Float16* gbl = gbh + 512;

    // ---- fragment LDS offsets (read side of the swizzle), half units ----
    // raw = row*16 + q2*8; XOR half-bits 3..5 with row bits 2..4. All added
    // offsets (f*512, region bases 2048/4096/6144, dd*8192) are multiples
    // of 512 halfs -> commute with the XOR. Balanced: each half-wave's 32
    // lanes spread 4-per-bank-quad over all 8 quads (linear surjection
    // l31 -> {b2, b0^b3, b1^b4}).
    const int swz = ((l31 >> 2) & 7) << 3;
    const int ra = ((wm + l31) * 16 + q2 * 8) ^ swz;
    const int rb = ((wn + l31) * 16 + q2 * 8) ^ swz;

    floatx16 acc[2][2];
#pragma unroll
    for (int i = 0; i < 2; ++i)
#pragma unroll
        for (int j = 0; j < 2; ++j)
#pragma unroll
            for (int e = 0; e < 16; ++e) acc[i][j][e] = 0.f;

    STAGE(0, 0);
#pragma unroll 2
    for (int c = 0; c < 31; ++c) {
        const int d = c & 1;
        STAGE(d ^ 1, (c + 1) * 16);
        asm volatile("s_waitcnt vmcnt(4)" ::: "memory");
        __builtin_amdgcn_s_barrier();
        COMPUTE(d);
        __builtin_amdgcn_s_barrier();
        asm volatile("" ::: "memory");
    }
    asm volatile("s_waitcnt vmcnt(0)" ::: "memory");
    __builtin_amdgcn_s_barrier();
    COMPUTE(1);
    __syncthreads();   // full fence: all ds reads/loads done before Cs overwrite

    // ---- epilogue: acc -> LDS (four 32-row phases) -> LIF scan + FC2 ----
    float b1c[2];
#pragma unroll
    for (int fn = 0; fn < 2; ++fn) b1c[fn] = b1[n0 + wn + fn * 32 + l31];

    float mem = 0.f, ss = 0.f;

    // phase p covers tile rows [32p, 32p+32): written by waves 0,1 (wm=0)
    // for p<2 with fm=p, by waves 2,3 for p>=2 with fm=p-2.
#pragma unroll
    for (int p = 0; p < 4; ++p) {
        const int fm = p & 1;
        if ((w >> 1) == (p >> 1)) {
#pragma unroll
            for (int r = 0; r < 16; ++r) {
                const int row = (r & 3) + 8 * (r >> 2) + 4 * q2;  // 0..31
                float* dst = &sm.Cs[row * 128 + wn + l31];
#pragma unroll
                for (int fn = 0; fn < 2; ++fn)
                    dst[fn * 32] = acc[fm][fn][r] * ISC + b1c[fn];
            }
        }
        __syncthreads();
        if (tid < 128) {
            const int nt = (p == 3) ? 4 : 32;   // t 96..99 only in last phase
#pragma unroll 8
            for (int t = 0; t < nt; ++t) {
                float cv = sm.Cs[t * 128 + tid];
                float reset = (mem > 1.0f) ? 1.0f : 0.0f;
                mem = 0.9f * mem + cv - reset;
                ss += (mem > 1.0f) ? 1.0f : 0.0f;
            }
        }
        __syncthreads();
    }

    // ---- FC2: logits[b][c] += sum_h ss * W2[c][h] ----
    if (tid < 128) {
#pragma unroll
        for (int cc = 0; cc < C_; ++cc) {
            float v = ss * W2[cc * H_ + n0 + tid];
#pragma unroll
            for (int off = 32; off; off >>= 1) v += __shfl_down(v, off, 64);
            if (lane == 0) atomicAdd(&logits[b * C_ + cc], v);
        }
    }
}

extern "C" void kernel_launch(void* const* d_in, const int* in_sizes, int n_in,
                              void* d_out, int out_size, void* d_ws, size_t ws_size,
                              hipStream_t stream) {
    const float* x  = (const float*)d_in[0];
    const float* W1 = (const float*)d_in[1];
    const float* b1 = (const float*)d_in[2];
    const float* W2 = (const float*)d_in[3];
    const float* b2 = (const float*)d_in[4];
    float* out = (float*)d_out;

    // workspace: Asp [25600][1024] f16, Wsp [1024][1024] f16 directly after
    // (fused kernel's tail rows overread into Wsp by design).
    char* ws = (char*)d_ws;
    _Float16* Asp = (_Float16*)ws;
    _Float16* Wsp = (_Float16*)(ws + (size_t)M_ * KS_ * 2);

    hipLaunchKernelGGL(split_all, dim3((M_ + H_) * 64 / 256), dim3(256), 0, stream,
                       x, W1, b2, Asp, out);
    hipLaunchKernelGGL(snn_mfma, dim3(B_ * 8), dim3(256), 0, stream,
                       Asp, Wsp, b1, W2, out);
}

// Round 5
// 198.675 us; speedup vs baseline: 1.8274x; 1.2100x over previous
//
#include <hip/hip_runtime.h>

// SNN direction decoder — fused MFMA GEMM + LIF scan + FC2.
// B=256, T=100, I=512, H=1024, C=8.
// R9: fix R8's staging scatter via a PANELIZED WORKSPACE LAYOUT.
//  - R8 forensics: SQ_LDS_BANK_CONFLICT = 8 cy x every gload_lds (R5: 0).
//    Cause: chunk staging read 16-half column slices = 32B per row at 2KB
//    stride -> 32 scattered cachelines per gload_lds -> LDS write-return
//    serialization + 4x L2 transactions. Read-side swizzle is provably
//    balanced (4 lanes per 16B bank-quad) - not the problem.
//  - Fix: Asp/Wsp stored as [panel=row/32][s=hi|lo][chunk=k16/16][row&31][16]
//    so one (panel,s,chunk) cell = 32 rows x 32B = 1024B CONTIGUOUS = one
//    gload_lds (per-lane source; <=2 contiguous runs at panel straddle).
//  - Everything else identical to R8 (HW-validated): 128x128 block tile,
//    4 waves of 64x64, 32x32x16 f16 MFMA, dedup'd {Ah,Al,Bh,Bl} staging,
//    dbuf 16KB chunks, counted vmcnt(4) + raw s_barrier, swizzle pair
//    (read ^((l31>>2)&7)<<3 halfs / write via lane perm lp=lane^((lane>>3)&7)),
//    __launch_bounds__(256,2) (NEVER (256,3): 601MB scratch spill in R7).
// fp32 GEMM emulated as 3-term f16 (xh*wh + xh*wl + xl*wh), inputs
// pre-scaled 2^6, un-scaled 2^-12 at epilogue.

#define B_   256
#define T_   100
#define I_   512
#define H_   1024
#define C_   8
#define M_   (B_ * T_)        // 25600
#define SC   64.0f            // 2^6 pre-scale
#define ISC  (1.0f / 4096.0f) // 2^-12 epilogue un-scale

// Panel layout constants (all in halfs):
//   cell   = 32 rows * 16 halfs              = 512 halfs (1024 B)
//   s-half = 32 chunks * cell                = 16384
//   panel  = 2 * s-half                      = 32768 (64 KB)
#define CELL_  512
#define SHALF_ 16384
#define PANEL_ 32768

typedef _Float16 half8 __attribute__((ext_vector_type(8)));
typedef float floatx16 __attribute__((ext_vector_type(16)));

__device__ __forceinline__ void ld_g2l(const _Float16* g, _Float16* l) {
    // async global->LDS, 16B/lane; LDS dest = wave-uniform base + lane*16
    __builtin_amdgcn_global_load_lds(
        (const __attribute__((address_space(1))) void*)g,
        (__attribute__((address_space(3))) void*)l, 16, 0, 0);
}

// Splitter: wave-per-cell. Wave W < 25600 handles A cell (p=W>>5, c=W&31):
// reads x rows p*32+[0,32), fp32 cols c*16+[0,16) (64B contiguous per row),
// writes hi cell (1KB contiguous per wave) + lo cell at +SHALF_.
// Waves 25600..26623 do the same for W1 -> Wsp. Blocks 0..7 init logits.
__global__ void __launch_bounds__(256)
split_all(const float* __restrict__ x, const float* __restrict__ W1,
          const float* __restrict__ b2, _Float16* __restrict__ Asp,
          float* __restrict__ out) {
    const int tid = threadIdx.x;
    const int lane = tid & 63;
    int g = blockIdx.x * 256 + tid;
    if (g < B_ * C_) out[g] = 100.0f * b2[g & (C_ - 1)];

    const int W = blockIdx.x * 4 + (tid >> 6);   // global wave id, 0..26623
    const bool isA = (W < M_ / 32 * 32 / 32 * 1 * 32 * 32 / 32 ? (W < 800 * 32) : false);
    // (constant-folded: A waves are W < 25600)
    const int Wl = (W < 25600) ? W : (W - 25600);
    const int p = Wl >> 5;            // panel
    const int c = Wl & 31;            // chunk
    const int r = p * 32 + (lane >> 1);           // source row within matrix
    const int col = c * 16 + (lane & 1) * 8;      // fp32 column
    const float* src = (W < 25600) ? (x + (size_t)r * I_ + col)
                                   : (W1 + (size_t)r * I_ + col);
    float4 v0 = *(const float4*)(src);
    float4 v1 = *(const float4*)(src + 4);
    float vv[8] = {v0.x, v0.y, v0.z, v0.w, v1.x, v1.y, v1.z, v1.w};
    half8 hi, lo;
#pragma unroll
    for (int j = 0; j < 8; ++j) {
        float s = vv[j] * SC;
        _Float16 h = (_Float16)s;
        hi[j] = h;
        lo[j] = (_Float16)(s - (float)h);
    }
    // dest: (lane>>1)*16 + (lane&1)*8 == lane*8
    _Float16* base = Asp + ((W < 25600) ? 0 : (size_t)800 * PANEL_);
    _Float16* d = base + (size_t)p * PANEL_ + c * CELL_ + lane * 8;
    *(half8*)(d) = hi;
    *(half8*)(d + SHALF_) = lo;
}

#define MFMA32(A, Bv, Cacc) \
    Cacc = __builtin_amdgcn_mfma_f32_32x32x16_f16(A, Bv, Cacc, 0, 0, 0)

// One chunk = 16 k-halfs of each of {Ah, Al, Bh, Bl}.
// LDS buffer (halfs): Ah[128*16] @0 | Al @2048 | Bh[128*16] @4096 | Bl @6144.
// Buffer stride 8192 halfs (16 KB). Each wave stages its 32-row window
// (1024 B contiguous source AND dest) per region -> 4 gload_lds/wave/chunk.
#define STAGE(dd, cc) do {                                           \
    _Float16* lb = &sm.buf[0][0] + (dd) * 8192 + w * 512;            \
    ld_g2l(gah + (cc) * CELL_, lb);                                  \
    ld_g2l(gal + (cc) * CELL_, lb + 2048);                           \
    ld_g2l(gbh + (cc) * CELL_, lb + 4096);                           \
    ld_g2l(gbl + (cc) * CELL_, lb + 6144);                           \
} while (0)

// (ra + f*512 is safe: f*512 is a multiple of 512 halfs, above the XOR bits)
#define COMPUTE(dd) do {                                             \
    const _Float16* bb = &sm.buf[0][0] + (dd) * 8192;                \
    half8 ah[2], al[2], bh[2], bl[2];                                \
    _Pragma("unroll")                                                \
    for (int f = 0; f < 2; ++f) {                                    \
        ah[f] = *(const half8*)(bb + ra + f * 512);                  \
        al[f] = *(const half8*)(bb + 2048 + ra + f * 512);           \
        bh[f] = *(const half8*)(bb + 4096 + rb + f * 512);           \
        bl[f] = *(const half8*)(bb + 6144 + rb + f * 512);           \
    }                                                                \
    _Pragma("unroll")                                                \
    for (int fm = 0; fm < 2; ++fm) {                                 \
        _Pragma("unroll")                                            \
        for (int fn = 0; fn < 2; ++fn) {                             \
            MFMA32(ah[fm], bh[fn], acc[fm][fn]);                     \
            MFMA32(ah[fm], bl[fn], acc[fm][fn]);                     \
            MFMA32(al[fm], bh[fn], acc[fm][fn]);                     \
        }                                                            \
    }                                                                \
} while (0)

// Fused: C-tile[t 0..127][128 h], then LIF scan + FC2. One batch per block,
// 8 h-tiles of 128. XCD-swizzled: xcd=blk&7 owns batches [32*xcd, 32*xcd+32).
// A rows 100..127 overread into next batch / Wsp panels (masked in scan).
__global__ void __launch_bounds__(256, 2)
snn_mfma(const _Float16* __restrict__ Asp, const _Float16* __restrict__ Wsp,
         const float* __restrict__ b1, const float* __restrict__ W2,
         float* __restrict__ logits) {
    __shared__ union {
        __align__(16) _Float16 buf[2][8192];   // double-buffered chunk (32 KB)
        float Cs[32 * 128];                    // epilogue staging (16 KB)
    } sm;
    const int tid = threadIdx.x;
    const int lane = tid & 63;
    const int w = tid >> 6;

    const int xcd = blockIdx.x & 7;
    const int jj = blockIdx.x >> 3;        // 0..255 per-XCD sequence
    const int b  = xcd * 32 + (jj >> 3);   // batch 0..255
    const int n0 = (jj & 7) * 128;         // h tile offset

    const int wm = (w >> 1) * 64;   // wave's 64x64 sub-tile
    const int wn = (w & 1) * 64;
    const int l31 = lane & 31;
    const int q2 = lane >> 5;

    // ---- staging pointers (write side of the swizzle) ----
    // lane l's gload_lds writes LDS halfs [w*512 + l*8); it must carry the
    // data of logical lane lp = l ^ ((l>>3)&7) (involution), i.e. logical
    // row lp>>1, 8-half group lp&1. Panelized source address for that cell:
    const int lp = lane ^ ((lane >> 3) & 7);
    const int ra_row = b * T_ + w * 32 + (lp >> 1);        // A matrix row
    const int rb_row = n0 + w * 32 + (lp >> 1);            // B (W1) row
    const _Float16* gah = Asp + (size_t)(ra_row >> 5) * PANEL_
                              + (ra_row & 31) * 16 + (lp & 1) * 8;
    const _Float16* gal = gah + SHALF_;
    const _Float16* gbh = Wsp + (size_t)(rb_row >> 5) * PANEL_
                              + (rb_row & 31) * 16 + (lp & 1) * 8;
    const _Float16* gbl = gbh + SHALF_;

    // ---- fragment LDS offsets (read side of the swizzle), half units ----
    // raw = row*16 + q2*8; XOR half-bits 3..5 with row bits 2..4. All added
    // offsets (f*512, region bases 2048/4096/6144, dd*8192) are multiples
    // of 512 halfs -> commute with the XOR. Bank map quad = 2*(l31&3) ^
    // (l31>>2): exactly 4 lanes per 16B bank-quad -> conflict-free b128.
    const int swz = ((l31 >> 2) & 7) << 3;
    const int ra = ((wm + l31) * 16 + q2 * 8) ^ swz;
    const int rb = ((wn + l31) * 16 + q2 * 8) ^ swz;

    floatx16 acc[2][2];
#pragma unroll
    for (int i = 0; i < 2; ++i)
#pragma unroll
        for (int j = 0; j < 2; ++j)
#pragma unroll
            for (int e = 0; e < 16; ++e) acc[i][j][e] = 0.f;

    STAGE(0, 0);
#pragma unroll 2
    for (int c = 0; c < 31; ++c) {
        const int d = c & 1;
        STAGE(d ^ 1, c + 1);
        asm volatile("s_waitcnt vmcnt(4)" ::: "memory");
        __builtin_amdgcn_s_barrier();
        COMPUTE(d);
        __builtin_amdgcn_s_barrier();
        asm volatile("" ::: "memory");
    }
    asm volatile("s_waitcnt vmcnt(0)" ::: "memory");
    __builtin_amdgcn_s_barrier();
    COMPUTE(1);
    __syncthreads();   // full fence: all ds reads/loads done before Cs overwrite

    // ---- epilogue: acc -> LDS (four 32-row phases) -> LIF scan + FC2 ----
    float b1c[2];
#pragma unroll
    for (int fn = 0; fn < 2; ++fn) b1c[fn] = b1[n0 + wn + fn * 32 + l31];

    float mem = 0.f, ss = 0.f;

    // phase p covers tile rows [32p, 32p+32): written by waves 0,1 (wm=0)
    // for p<2 with fm=p, by waves 2,3 for p>=2 with fm=p-2.
#pragma unroll
    for (int p = 0; p < 4; ++p) {
        const int fm = p & 1;
        if ((w >> 1) == (p >> 1)) {
#pragma unroll
            for (int r = 0; r < 16; ++r) {
                const int row = (r & 3) + 8 * (r >> 2) + 4 * q2;  // 0..31
                float* dst = &sm.Cs[row * 128 + wn + l31];
#pragma unroll
                for (int fn = 0; fn < 2; ++fn)
                    dst[fn * 32] = acc[fm][fn][r] * ISC + b1c[fn];
            }
        }
        __syncthreads();
        if (tid < 128) {
            const int nt = (p == 3) ? 4 : 32;   // t 96..99 only in last phase
#pragma unroll 8
            for (int t = 0; t < nt; ++t) {
                float cv = sm.Cs[t * 128 + tid];
                float reset = (mem > 1.0f) ? 1.0f : 0.0f;
                mem = 0.9f * mem + cv - reset;
                ss += (mem > 1.0f) ? 1.0f : 0.0f;
            }
        }
        __syncthreads();
    }

    // ---- FC2: logits[b][c] += sum_h ss * W2[c][h] ----
    if (tid < 128) {
#pragma unroll
        for (int cc = 0; cc < C_; ++cc) {
            float v = ss * W2[cc * H_ + n0 + tid];
#pragma unroll
            for (int off = 32; off; off >>= 1) v += __shfl_down(v, off, 64);
            if (lane == 0) atomicAdd(&logits[b * C_ + cc], v);
        }
    }
}

extern "C" void kernel_launch(void* const* d_in, const int* in_sizes, int n_in,
                              void* d_out, int out_size, void* d_ws, size_t ws_size,
                              hipStream_t stream) {
    const float* x  = (const float*)d_in[0];
    const float* W1 = (const float*)d_in[1];
    const float* b1 = (const float*)d_in[2];
    const float* W2 = (const float*)d_in[3];
    const float* b2 = (const float*)d_in[4];
    float* out = (float*)d_out;

    // workspace: Asp = 800 panels (52.4 MB), Wsp = 32 panels (2 MB) directly
    // after (fused kernel's tail rows overread into Wsp panels by design).
    char* ws = (char*)d_ws;
    _Float16* Asp = (_Float16*)ws;
    _Float16* Wsp = Asp + (size_t)800 * PANEL_;

    // 26624 waves (25600 A cells + 1024 W1 cells) = 6656 blocks
    hipLaunchKernelGGL(split_all, dim3(6656), dim3(256), 0, stream,
                       x, W1, b2, Asp, out);
    hipLaunchKernelGGL(snn_mfma, dim3(B_ * 8), dim3(256), 0, stream,
                       Asp, Wsp, b1, W2, out);
}